// Round 1
// baseline (865.569 us; speedup 1.0000x reference)
//
#include <hip/hip_runtime.h>
#include <math.h>

#define B_ 64
#define N_ 64
#define C_ 8
#define F_ 256
#define K_ 2048    // C_*F_
#define NO_ 2048   // OC_*OF_

// ---------------------------------------------------------------------------
// s1[b] = sum_{c,f} x[b,c,f] * w1sum[f]; s2[b,n] = sum_{c,f} nb[b,n,c,f]*w2sum[f]
__global__ __launch_bounds__(256) void sums_k(const float* __restrict__ x,
        const float* __restrict__ nb, const float* __restrict__ W1,
        const float* __restrict__ W2, float* __restrict__ s1,
        float* __restrict__ s2) {
    int blk = blockIdx.x;
    int f = threadIdx.x;
    float val;
    if (blk < B_ * N_) {
        const float* base = nb + (size_t)blk * (C_ * F_);
        float wsum = 0.f;
        #pragma unroll
        for (int k = 0; k < C_; ++k) wsum += W2[k * F_ + f];
        float cs = 0.f;
        #pragma unroll
        for (int c = 0; c < C_; ++c) cs += base[c * F_ + f];
        val = cs * wsum;
    } else {
        int b = blk - B_ * N_;
        const float* base = x + (size_t)b * (C_ * F_);
        float wsum = 0.f;
        #pragma unroll
        for (int k = 0; k < C_; ++k) wsum += W1[k * F_ + f];
        float cs = 0.f;
        #pragma unroll
        for (int c = 0; c < C_; ++c) cs += base[c * F_ + f];
        val = cs * wsum;
    }
    __shared__ float red[256];
    red[f] = val;
    __syncthreads();
    for (int s = 128; s > 0; s >>= 1) {
        if (f < s) red[f] += red[f + s];
        __syncthreads();
    }
    if (f == 0) {
        if (blk < B_ * N_) s2[blk] = red[0];
        else s1[blk - B_ * N_] = red[0];
    }
}

// ---------------------------------------------------------------------------
// t[b,c,d] = s1[b] * sum_n nb[b,n,c,d] * s2[b,n]
__global__ __launch_bounds__(256) void t_k(const float* __restrict__ nb,
        const float* __restrict__ s1, const float* __restrict__ s2,
        float* __restrict__ t) {
    int blk = blockIdx.x;  // b*C_ + c
    int b = blk / C_, c = blk % C_;
    int d = threadIdx.x;
    float acc = 0.f;
    const float* p = nb + ((size_t)(b * N_) * C_ + c) * F_ + d;
    const float* s2p = s2 + b * N_;
    for (int n = 0; n < N_; ++n) acc += p[(size_t)n * C_ * F_] * s2p[n];
    t[(size_t)blk * F_ + d] = acc * s1[b];
}

// ---------------------------------------------------------------------------
// denom[b,a,d] = 1e-7 + sum_c |sgnroot(x[b,c,a]*t[b,c,d] + x[b,c,d]*t[b,c,a])|
__global__ __launch_bounds__(256) void denom_k(const float* __restrict__ x,
        const float* __restrict__ t, float* __restrict__ denom) {
    int blk = blockIdx.x;  // b*F_ + a
    int b = blk >> 8, a = blk & 255;
    int d = threadIdx.x;
    float acc = 1e-7f;
    #pragma unroll
    for (int c = 0; c < C_; ++c) {
        size_t o = ((size_t)b * C_ + c) * F_;
        float xa = x[o + a], ta = t[o + a];
        float xd = x[o + d], td = t[o + d];
        float v = xa * td + xd * ta;
        float r = sqrtf(fmaxf(fabsf(v), 1e-8f));
        acc += (v != 0.f) ? r : 0.f;
    }
    denom[(size_t)blk * F_ + d] = acc;
}

__device__ __forceinline__ float sgnroot_dev(float v) {
    float r = sqrtf(fmaxf(fabsf(v), 1e-8f));
    return (v > 0.f) ? r : ((v < 0.f) ? -r : 0.f);
}

// ---------------------------------------------------------------------------
// zx[b,c,a] = sum_d adj[b,c,a,d] * x[b,c,d]
__global__ __launch_bounds__(256) void zx_k(const float* __restrict__ x,
        const float* __restrict__ t, const float* __restrict__ denom,
        float* __restrict__ zx) {
    int blk = blockIdx.x;  // b*C_ + c
    int b = blk / C_;
    int a = threadIdx.x;
    __shared__ float xs[F_], ts[F_];
    xs[a] = x[(size_t)blk * F_ + a];
    ts[a] = t[(size_t)blk * F_ + a];
    __syncthreads();
    float xa = xs[a], ta = ts[a], acc = 0.f;
    const float* drow = denom + ((size_t)b * F_ + a) * F_;
    for (int d0 = 0; d0 < F_; d0 += 4) {
        float4 dn = *(const float4*)(drow + d0);
        float dens[4] = {dn.x, dn.y, dn.z, dn.w};
        #pragma unroll
        for (int j = 0; j < 4; ++j) {
            int d = d0 + j;
            float g = sgnroot_dev(xa * ts[d] + xs[d] * ta);
            acc += (g / dens[j]) * xs[d];
        }
    }
    zx[(size_t)blk * F_ + a] = acc;
}

// ---------------------------------------------------------------------------
// zn[b,n,c,a] = sum_d adj[b,c,a,d] * nb[b,n,c,d], adj recomputed on the fly.
// One block per (b, c, n-half); thread = a; 32 accumulators per thread.
#define ZN_NT 32
#define ZN_PAD 36
__global__ __launch_bounds__(256) void zn_k(const float* __restrict__ x,
        const float* __restrict__ t, const float* __restrict__ denom,
        const float* __restrict__ nb, float* __restrict__ zn) {
    int blk = blockIdx.x;  // (b*C_ + c)*2 + nh
    int nh = blk & 1;
    int bc = blk >> 1;
    int b = bc / C_, c = bc % C_;
    int a = threadIdx.x;
    __shared__ float xs[F_], ts[F_];
    __shared__ float nbT[F_ * ZN_PAD];  // nbT[d][n], padded rows (16B aligned)
    xs[a] = x[(size_t)bc * F_ + a];
    ts[a] = t[(size_t)bc * F_ + a];
    {
        int d = a;
        const float* p = nb + (((size_t)(b * N_ + nh * ZN_NT)) * C_ + c) * F_ + d;
        for (int n = 0; n < ZN_NT; ++n)
            nbT[d * ZN_PAD + n] = p[(size_t)n * C_ * F_];
    }
    __syncthreads();
    float xa = xs[a], ta = ts[a];
    float acc[ZN_NT];
    #pragma unroll
    for (int n = 0; n < ZN_NT; ++n) acc[n] = 0.f;
    const float* drow = denom + ((size_t)b * F_ + a) * F_;
    for (int d0 = 0; d0 < F_; d0 += 4) {
        float4 dn = *(const float4*)(drow + d0);
        float dens[4] = {dn.x, dn.y, dn.z, dn.w};
        #pragma unroll
        for (int j = 0; j < 4; ++j) {
            int d = d0 + j;
            float g = sgnroot_dev(xa * ts[d] + xs[d] * ta);
            float adj = g / dens[j];
            const float* row = &nbT[d * ZN_PAD];
            #pragma unroll
            for (int n4 = 0; n4 < ZN_NT; n4 += 4) {
                float4 nv = *(const float4*)(row + n4);
                acc[n4 + 0] += adj * nv.x;
                acc[n4 + 1] += adj * nv.y;
                acc[n4 + 2] += adj * nv.z;
                acc[n4 + 3] += adj * nv.w;
            }
        }
    }
    #pragma unroll
    for (int n = 0; n < ZN_NT; ++n) {
        int nn = nh * ZN_NT + n;
        zn[(((size_t)(b * N_ + nn)) * C_ + c) * F_ + a] = acc[n];
    }
}

// ---------------------------------------------------------------------------
// C[M,2048] = A[M,2048] @ Bm[2048,2048]^T   (fp32 64x64 tile, 4x4 per thread)
__global__ __launch_bounds__(256) void gemm_nt_k(const float* __restrict__ A,
        const float* __restrict__ Bm, float* __restrict__ Cm, int M) {
    const int K = K_;
    int col0 = blockIdx.x * 64;
    int row0 = blockIdx.y * 64;
    int tid = threadIdx.x;
    int tx = tid & 15, ty = tid >> 4;
    __shared__ float As[16][68];
    __shared__ float Bs[16][68];
    float acc[4][4] = {};
    int lr = tid >> 2;        // 0..63
    int lc = (tid & 3) * 4;   // 0,4,8,12
    const float* Ap = A + (size_t)(row0 + lr) * K + lc;
    const float* Bp = Bm + (size_t)(col0 + lr) * K + lc;
    for (int k0 = 0; k0 < K; k0 += 16) {
        float4 a4 = *(const float4*)(Ap + k0);
        float4 b4 = *(const float4*)(Bp + k0);
        __syncthreads();
        As[lc + 0][lr] = a4.x; As[lc + 1][lr] = a4.y;
        As[lc + 2][lr] = a4.z; As[lc + 3][lr] = a4.w;
        Bs[lc + 0][lr] = b4.x; Bs[lc + 1][lr] = b4.y;
        Bs[lc + 2][lr] = b4.z; Bs[lc + 3][lr] = b4.w;
        __syncthreads();
        #pragma unroll
        for (int kk = 0; kk < 16; ++kk) {
            float4 av = *(const float4*)&As[kk][ty * 4];
            float4 bv = *(const float4*)&Bs[kk][tx * 4];
            float avr[4] = {av.x, av.y, av.z, av.w};
            float bvr[4] = {bv.x, bv.y, bv.z, bv.w};
            #pragma unroll
            for (int i = 0; i < 4; ++i)
                #pragma unroll
                for (int j = 0; j < 4; ++j)
                    acc[i][j] += avr[i] * bvr[j];
        }
    }
    #pragma unroll
    for (int i = 0; i < 4; ++i) {
        float4 o = make_float4(acc[i][0], acc[i][1], acc[i][2], acc[i][3]);
        *(float4*)(Cm + (size_t)(row0 + ty * 4 + i) * NO_ + col0 + tx * 4) = o;
    }
}

// ---------------------------------------------------------------------------
extern "C" void kernel_launch(void* const* d_in, const int* in_sizes, int n_in,
                              void* d_out, int out_size, void* d_ws, size_t ws_size,
                              hipStream_t stream) {
    const float* x  = (const float*)d_in[0];
    const float* nb = (const float*)d_in[1];
    const float* W1 = (const float*)d_in[2];
    const float* W2 = (const float*)d_in[3];
    const float* Wc = (const float*)d_in[4];
    float* out = (float*)d_out;
    float* ws = (float*)d_ws;

    // workspace layout (floats): total 12,849,216 f = 51.4 MB
    float* s1    = ws;            // 64
    float* s2    = ws + 64;       // 4096
    float* t     = ws + 4160;     // 131072
    float* zx    = ws + 135232;   // 131072
    float* denom = ws + 266304;   // 4194304 (B*F*F)
    float* zn    = ws + 4460608;  // 8388608 (B*N*C*F)

    hipLaunchKernelGGL(sums_k, dim3(B_ * N_ + B_), dim3(256), 0, stream,
                       x, nb, W1, W2, s1, s2);
    hipLaunchKernelGGL(t_k, dim3(B_ * C_), dim3(256), 0, stream, nb, s1, s2, t);
    hipLaunchKernelGGL(denom_k, dim3(B_ * F_), dim3(256), 0, stream, x, t, denom);
    hipLaunchKernelGGL(zx_k, dim3(B_ * C_), dim3(256), 0, stream, x, t, denom, zx);
    hipLaunchKernelGGL(zn_k, dim3(B_ * C_ * 2), dim3(256), 0, stream,
                       x, t, denom, nb, zn);
    // x_out: 64 rows -> d_out[0 .. 131072)
    hipLaunchKernelGGL(gemm_nt_k, dim3(32, 1), dim3(256), 0, stream,
                       zx, Wc, out, 64);
    // n_out: 4096 rows -> d_out[131072 ..)
    hipLaunchKernelGGL(gemm_nt_k, dim3(32, 64), dim3(256), 0, stream,
                       zn, Wc, out + 131072, 4096);
}

// Round 2
// 376.717 us; speedup vs baseline: 2.2977x; 2.2977x over previous
//
#include <hip/hip_runtime.h>
#include <hip/hip_bf16.h>
#include <math.h>

#define B_ 64
#define N_ 64
#define C_ 8
#define F_ 256
#define K_ 2048    // C_*F_
#define NO_ 2048   // OC_*OF_
#define M_TOT 4160 // 64 (zx rows) + 4096 (zn rows)

typedef __attribute__((ext_vector_type(8))) short bf16x8;  // 8 bf16 = 4 VGPRs
typedef __attribute__((ext_vector_type(4))) float f32x4;

// ---------------------------------------------------------------------------
// s1[b] = sum_{c,f} x[b,c,f] * w1sum[f]; s2[b,n] = sum_{c,f} nb[b,n,c,f]*w2sum[f]
__global__ __launch_bounds__(256) void sums_k(const float* __restrict__ x,
        const float* __restrict__ nb, const float* __restrict__ W1,
        const float* __restrict__ W2, float* __restrict__ s1,
        float* __restrict__ s2) {
    int blk = blockIdx.x;
    int f = threadIdx.x;
    float val;
    if (blk < B_ * N_) {
        const float* base = nb + (size_t)blk * (C_ * F_);
        float wsum = 0.f;
        #pragma unroll
        for (int k = 0; k < C_; ++k) wsum += W2[k * F_ + f];
        float cs = 0.f;
        #pragma unroll
        for (int c = 0; c < C_; ++c) cs += base[c * F_ + f];
        val = cs * wsum;
    } else {
        int b = blk - B_ * N_;
        const float* base = x + (size_t)b * (C_ * F_);
        float wsum = 0.f;
        #pragma unroll
        for (int k = 0; k < C_; ++k) wsum += W1[k * F_ + f];
        float cs = 0.f;
        #pragma unroll
        for (int c = 0; c < C_; ++c) cs += base[c * F_ + f];
        val = cs * wsum;
    }
    __shared__ float red[256];
    red[f] = val;
    __syncthreads();
    for (int s = 128; s > 0; s >>= 1) {
        if (f < s) red[f] += red[f + s];
        __syncthreads();
    }
    if (f == 0) {
        if (blk < B_ * N_) s2[blk] = red[0];
        else s1[blk - B_ * N_] = red[0];
    }
}

// ---------------------------------------------------------------------------
// t[b,c,d] = s1[b] * sum_n nb[b,n,c,d] * s2[b,n]
__global__ __launch_bounds__(256) void t_k(const float* __restrict__ nb,
        const float* __restrict__ s1, const float* __restrict__ s2,
        float* __restrict__ t) {
    int blk = blockIdx.x;  // b*C_ + c
    int b = blk / C_, c = blk % C_;
    int d = threadIdx.x;
    float acc = 0.f;
    const float* p = nb + ((size_t)(b * N_) * C_ + c) * F_ + d;
    const float* s2p = s2 + b * N_;
    for (int n = 0; n < N_; ++n) acc += p[(size_t)n * C_ * F_] * s2p[n];
    t[(size_t)blk * F_ + d] = acc * s1[b];
}

// ---------------------------------------------------------------------------
// denom[b,a,d] = 1e-7 + sum_c |sgnroot(x[b,c,a]*t[b,c,d] + x[b,c,d]*t[b,c,a])|
__global__ __launch_bounds__(256) void denom_k(const float* __restrict__ x,
        const float* __restrict__ t, float* __restrict__ denom) {
    int blk = blockIdx.x;  // b*F_ + a
    int b = blk >> 8, a = blk & 255;
    int d = threadIdx.x;
    float acc = 1e-7f;
    #pragma unroll
    for (int c = 0; c < C_; ++c) {
        size_t o = ((size_t)b * C_ + c) * F_;
        float xa = x[o + a], ta = t[o + a];
        float xd = x[o + d], td = t[o + d];
        float v = xa * td + xd * ta;
        float r = sqrtf(fmaxf(fabsf(v), 1e-8f));
        acc += (v != 0.f) ? r : 0.f;
    }
    denom[(size_t)blk * F_ + d] = acc;
}

__device__ __forceinline__ float sgnroot_dev(float v) {
    float r = sqrtf(fmaxf(fabsf(v), 1e-8f));
    return (v > 0.f) ? r : ((v < 0.f) ? -r : 0.f);
}

// ---------------------------------------------------------------------------
// zx[b,c,a] = sum_d adj[b,c,a,d] * x[b,c,d]  -> bf16 into Abuf row b, col c*F+a
__global__ __launch_bounds__(256) void zx_k(const float* __restrict__ x,
        const float* __restrict__ t, const float* __restrict__ denom,
        __hip_bfloat16* __restrict__ Abuf) {
    int blk = blockIdx.x;  // b*C_ + c
    int b = blk / C_, c = blk % C_;
    int a = threadIdx.x;
    __shared__ float xs[F_], ts[F_];
    xs[a] = x[(size_t)blk * F_ + a];
    ts[a] = t[(size_t)blk * F_ + a];
    __syncthreads();
    float xa = xs[a], ta = ts[a], acc = 0.f;
    const float* drow = denom + ((size_t)b * F_ + a) * F_;
    for (int d0 = 0; d0 < F_; d0 += 4) {
        float4 dn = *(const float4*)(drow + d0);
        float dens[4] = {dn.x, dn.y, dn.z, dn.w};
        #pragma unroll
        for (int j = 0; j < 4; ++j) {
            int d = d0 + j;
            float g = sgnroot_dev(xa * ts[d] + xs[d] * ta);
            acc += (g / dens[j]) * xs[d];
        }
    }
    Abuf[(size_t)b * K_ + c * F_ + a] = __float2bfloat16(acc);
}

// ---------------------------------------------------------------------------
// zn[b,n,c,a] = sum_d adj[b,c,a,d] * nb[b,n,c,d] -> bf16 into Abuf row
// 64 + b*N + n, col c*F+a. adj recomputed on the fly.
#define ZN_NT 32
#define ZN_PAD 36
__global__ __launch_bounds__(256) void zn_k(const float* __restrict__ x,
        const float* __restrict__ t, const float* __restrict__ denom,
        const float* __restrict__ nb, __hip_bfloat16* __restrict__ Abuf) {
    int blk = blockIdx.x;  // (b*C_ + c)*2 + nh
    int nh = blk & 1;
    int bc = blk >> 1;
    int b = bc / C_, c = bc % C_;
    int a = threadIdx.x;
    __shared__ float xs[F_], ts[F_];
    __shared__ float nbT[F_ * ZN_PAD];  // nbT[d][n]
    xs[a] = x[(size_t)bc * F_ + a];
    ts[a] = t[(size_t)bc * F_ + a];
    {
        int d = a;
        const float* p = nb + (((size_t)(b * N_ + nh * ZN_NT)) * C_ + c) * F_ + d;
        for (int n = 0; n < ZN_NT; ++n)
            nbT[d * ZN_PAD + n] = p[(size_t)n * C_ * F_];
    }
    __syncthreads();
    float xa = xs[a], ta = ts[a];
    float acc[ZN_NT];
    #pragma unroll
    for (int n = 0; n < ZN_NT; ++n) acc[n] = 0.f;
    const float* drow = denom + ((size_t)b * F_ + a) * F_;
    for (int d0 = 0; d0 < F_; d0 += 4) {
        float4 dn = *(const float4*)(drow + d0);
        float dens[4] = {dn.x, dn.y, dn.z, dn.w};
        #pragma unroll
        for (int j = 0; j < 4; ++j) {
            int d = d0 + j;
            float g = sgnroot_dev(xa * ts[d] + xs[d] * ta);
            float adj = g / dens[j];
            const float* row = &nbT[d * ZN_PAD];
            #pragma unroll
            for (int n4 = 0; n4 < ZN_NT; n4 += 4) {
                float4 nv = *(const float4*)(row + n4);
                acc[n4 + 0] += adj * nv.x;
                acc[n4 + 1] += adj * nv.y;
                acc[n4 + 2] += adj * nv.z;
                acc[n4 + 3] += adj * nv.w;
            }
        }
    }
    #pragma unroll
    for (int n = 0; n < ZN_NT; ++n) {
        int nn = nh * ZN_NT + n;
        Abuf[(size_t)(64 + b * N_ + nn) * K_ + c * F_ + a] =
            __float2bfloat16(acc[n]);
    }
}

// ---------------------------------------------------------------------------
// Wc (2048x2048 fp32) -> bf16
__global__ __launch_bounds__(256) void wc_cvt_k(const float* __restrict__ Wc,
        __hip_bfloat16* __restrict__ Bbuf) {
    int i = (blockIdx.x * 256 + threadIdx.x) * 4;
    float4 v = *(const float4*)(Wc + i);
    Bbuf[i + 0] = __float2bfloat16(v.x);
    Bbuf[i + 1] = __float2bfloat16(v.y);
    Bbuf[i + 2] = __float2bfloat16(v.z);
    Bbuf[i + 3] = __float2bfloat16(v.w);
}

// ---------------------------------------------------------------------------
// C[M_TOT, 2048] = A[M_TOT, 2048] @ B[2048, 2048]^T, bf16 inputs, fp32 out.
// m97 structure: 128x128 tile, BK=32, 4 waves (2x2 of 64x64), 16x16x32 MFMA,
// global_load_lds width=16, 2-barrier K-loop.
__global__ __launch_bounds__(256) void gemm_bf16_k(
        const __hip_bfloat16* __restrict__ A,
        const __hip_bfloat16* __restrict__ Bm,
        float* __restrict__ Cm) {
    __shared__ char ldsA[128 * 32 * 2] __attribute__((aligned(16)));  // 8KB
    __shared__ char ldsB[128 * 32 * 2] __attribute__((aligned(16)));  // 8KB
    const int t = threadIdx.x;
    const int wave = t >> 6;
    const int lane = t & 63;
    const int col0 = blockIdx.x * 128;
    const int row0 = blockIdx.y * 128;
    const int wrow0 = (wave & 1) * 64;
    const int wcol0 = (wave >> 1) * 64;

    // staging address mapping: chunk e (16B) -> lds offset e*16,
    // covers row = e>>2 (0..127), kchunk = e&3 (8 bf16 each)
    const int rA0 = t >> 2;            // issue 0 row
    const int kc = (t & 3) * 8;        // k offset within 32
    // clamp rows so tile 32 (rows 4096..4223) stays in-bounds
    const int grA0 = min(row0 + rA0, M_TOT - 1);
    const int grA1 = min(row0 + rA0 + 64, M_TOT - 1);
    const int gcB0 = col0 + rA0;       // Wc rows are output cols (NT)
    const int gcB1 = col0 + rA0 + 64;
    const char* ldsA_u0 = ldsA + ((t >> 6) << 6) * 16;         // wave-uniform
    const char* ldsA_u1 = ldsA + 4096 + ((t >> 6) << 6) * 16;
    const char* ldsB_u0 = ldsB + ((t >> 6) << 6) * 16;
    const char* ldsB_u1 = ldsB + 4096 + ((t >> 6) << 6) * 16;

    f32x4 acc[4][4] = {};

    for (int k0 = 0; k0 < K_; k0 += 32) {
        __syncthreads();  // previous iteration's frag reads done
        __builtin_amdgcn_global_load_lds(
            (const __attribute__((address_space(1))) void*)(A + (size_t)grA0 * K_ + k0 + kc),
            (__attribute__((address_space(3))) void*)ldsA_u0, 16, 0, 0);
        __builtin_amdgcn_global_load_lds(
            (const __attribute__((address_space(1))) void*)(A + (size_t)grA1 * K_ + k0 + kc),
            (__attribute__((address_space(3))) void*)ldsA_u1, 16, 0, 0);
        __builtin_amdgcn_global_load_lds(
            (const __attribute__((address_space(1))) void*)(Bm + (size_t)gcB0 * K_ + k0 + kc),
            (__attribute__((address_space(3))) void*)ldsB_u0, 16, 0, 0);
        __builtin_amdgcn_global_load_lds(
            (const __attribute__((address_space(1))) void*)(Bm + (size_t)gcB1 * K_ + k0 + kc),
            (__attribute__((address_space(3))) void*)ldsB_u1, 16, 0, 0);
        __syncthreads();  // drains vmcnt -> staging visible

        bf16x8 af[4], bf[4];
        #pragma unroll
        for (int rb = 0; rb < 4; ++rb) {
            int off = (wrow0 + rb * 16 + (lane & 15)) * 64 + (lane >> 4) * 16;
            af[rb] = *(const bf16x8*)(ldsA + off);
        }
        #pragma unroll
        for (int cb = 0; cb < 4; ++cb) {
            int off = (wcol0 + cb * 16 + (lane & 15)) * 64 + (lane >> 4) * 16;
            bf[cb] = *(const bf16x8*)(ldsB + off);
        }
        #pragma unroll
        for (int rb = 0; rb < 4; ++rb)
            #pragma unroll
            for (int cb = 0; cb < 4; ++cb)
                acc[rb][cb] = __builtin_amdgcn_mfma_f32_16x16x32_bf16(
                    af[rb], bf[cb], acc[rb][cb], 0, 0, 0);
    }

    // C/D layout: col = lane&15, row = (lane>>4)*4 + i
    #pragma unroll
    for (int rb = 0; rb < 4; ++rb) {
        int rowbase = row0 + wrow0 + rb * 16 + (lane >> 4) * 4;
        #pragma unroll
        for (int cb = 0; cb < 4; ++cb) {
            int col = col0 + wcol0 + cb * 16 + (lane & 15);
            #pragma unroll
            for (int i = 0; i < 4; ++i) {
                int row = rowbase + i;
                if (row < M_TOT)
                    Cm[(size_t)row * NO_ + col] = acc[rb][cb][i];
            }
        }
    }
}

// ---------------------------------------------------------------------------
extern "C" void kernel_launch(void* const* d_in, const int* in_sizes, int n_in,
                              void* d_out, int out_size, void* d_ws, size_t ws_size,
                              hipStream_t stream) {
    const float* x  = (const float*)d_in[0];
    const float* nb = (const float*)d_in[1];
    const float* W1 = (const float*)d_in[2];
    const float* W2 = (const float*)d_in[3];
    const float* Wc = (const float*)d_in[4];
    float* out = (float*)d_out;
    float* ws = (float*)d_ws;

    // workspace layout
    float* s1    = ws;            // 64 f
    float* s2    = ws + 64;       // 4096 f
    float* t     = ws + 4160;     // 131072 f
    float* denom = ws + 135232;   // 4194304 f (B*F*F)
    // bf16 region starts at float offset 4329536 (byte 17,318,144; 16B aligned)
    __hip_bfloat16* Abuf = (__hip_bfloat16*)(ws + 4329536);   // 4160*2048 bf16
    __hip_bfloat16* Bbuf = Abuf + (size_t)M_TOT * K_;         // 2048*2048 bf16

    hipLaunchKernelGGL(sums_k, dim3(B_ * N_ + B_), dim3(256), 0, stream,
                       x, nb, W1, W2, s1, s2);
    hipLaunchKernelGGL(t_k, dim3(B_ * C_), dim3(256), 0, stream, nb, s1, s2, t);
    hipLaunchKernelGGL(denom_k, dim3(B_ * F_), dim3(256), 0, stream, x, t, denom);
    hipLaunchKernelGGL(wc_cvt_k, dim3((K_ * NO_) / 1024), dim3(256), 0, stream,
                       Wc, Bbuf);
    hipLaunchKernelGGL(zx_k, dim3(B_ * C_), dim3(256), 0, stream, x, t, denom, Abuf);
    hipLaunchKernelGGL(zn_k, dim3(B_ * C_ * 2), dim3(256), 0, stream,
                       x, t, denom, nb, Abuf);
    // one fused GEMM writes x_out (rows 0..64) and n_out (rows 64..4160)
    hipLaunchKernelGGL(gemm_bf16_k, dim3(16, 33), dim3(256), 0, stream,
                       Abuf, Bbuf, out);
}

// Round 4
// 267.104 us; speedup vs baseline: 3.2406x; 1.4104x over previous
//
#include <hip/hip_runtime.h>
#include <hip/hip_bf16.h>
#include <math.h>

#define B_ 64
#define N_ 64
#define C_ 8
#define F_ 256
#define K_ 2048    // C_*F_
#define NO_ 2048   // OC_*OF_
#define M_TOT 4160 // 64 (zx rows) + 4096 (zn rows)

typedef __attribute__((ext_vector_type(8))) short bf16x8;  // 8 bf16 = 4 VGPRs
typedef __attribute__((ext_vector_type(4))) float f32x4;

// ---------------------------------------------------------------------------
// s1[b] = sum_{c,f} x[b,c,f] * w1sum[f]; s2[b,n] = sum_{c,f} nb[b,n,c,f]*w2sum[f]
__global__ __launch_bounds__(256) void sums_k(const float* __restrict__ x,
        const float* __restrict__ nb, const float* __restrict__ W1,
        const float* __restrict__ W2, float* __restrict__ s1,
        float* __restrict__ s2) {
    int blk = blockIdx.x;
    int f = threadIdx.x;
    float val;
    if (blk < B_ * N_) {
        const float* base = nb + (size_t)blk * (C_ * F_);
        float wsum = 0.f;
        #pragma unroll
        for (int k = 0; k < C_; ++k) wsum += W2[k * F_ + f];
        float cs = 0.f;
        #pragma unroll
        for (int c = 0; c < C_; ++c) cs += base[c * F_ + f];
        val = cs * wsum;
    } else {
        int b = blk - B_ * N_;
        const float* base = x + (size_t)b * (C_ * F_);
        float wsum = 0.f;
        #pragma unroll
        for (int k = 0; k < C_; ++k) wsum += W1[k * F_ + f];
        float cs = 0.f;
        #pragma unroll
        for (int c = 0; c < C_; ++c) cs += base[c * F_ + f];
        val = cs * wsum;
    }
    __shared__ float red[256];
    red[f] = val;
    __syncthreads();
    for (int s = 128; s > 0; s >>= 1) {
        if (f < s) red[f] += red[f + s];
        __syncthreads();
    }
    if (f == 0) {
        if (blk < B_ * N_) s2[blk] = red[0];
        else s1[blk - B_ * N_] = red[0];
    }
}

// ---------------------------------------------------------------------------
// t[b,c,d] = s1[b] * sum_n nb[b,n,c,d] * s2[b,n]
__global__ __launch_bounds__(256) void t_k(const float* __restrict__ nb,
        const float* __restrict__ s1, const float* __restrict__ s2,
        float* __restrict__ t) {
    int blk = blockIdx.x;  // b*C_ + c
    int b = blk / C_, c = blk % C_;
    int d = threadIdx.x;
    float acc = 0.f;
    const float* p = nb + ((size_t)(b * N_) * C_ + c) * F_ + d;
    const float* s2p = s2 + b * N_;
    for (int n = 0; n < N_; ++n) acc += p[(size_t)n * C_ * F_] * s2p[n];
    t[(size_t)blk * F_ + d] = acc * s1[b];
}

// ---------------------------------------------------------------------------
// denom[b,a,d] = 1e-7 + sum_c |sgnroot(x[b,c,a]*t[b,c,d] + x[b,c,d]*t[b,c,a])|
__global__ __launch_bounds__(256) void denom_k(const float* __restrict__ x,
        const float* __restrict__ t, float* __restrict__ denom) {
    int blk = blockIdx.x;  // b*F_ + a
    int b = blk >> 8, a = blk & 255;
    int d = threadIdx.x;
    float acc = 1e-7f;
    #pragma unroll
    for (int c = 0; c < C_; ++c) {
        size_t o = ((size_t)b * C_ + c) * F_;
        float xa = x[o + a], ta = t[o + a];
        float xd = x[o + d], td = t[o + d];
        float v = xa * td + xd * ta;
        float r = sqrtf(fmaxf(fabsf(v), 1e-8f));
        acc += (v != 0.f) ? r : 0.f;
    }
    denom[(size_t)blk * F_ + d] = acc;
}

__device__ __forceinline__ float sgnroot_dev(float v) {
    float r = sqrtf(fmaxf(fabsf(v), 1e-8f));
    return (v > 0.f) ? r : ((v < 0.f) ? -r : 0.f);
}

// ---------------------------------------------------------------------------
// Wc (2048x2048 fp32) -> bf16
__global__ __launch_bounds__(256) void wc_cvt_k(const float* __restrict__ Wc,
        __hip_bfloat16* __restrict__ Bbuf) {
    int i = (blockIdx.x * 256 + threadIdx.x) * 4;
    float4 v = *(const float4*)(Wc + i);
    Bbuf[i + 0] = __float2bfloat16(v.x);
    Bbuf[i + 1] = __float2bfloat16(v.y);
    Bbuf[i + 2] = __float2bfloat16(v.z);
    Bbuf[i + 3] = __float2bfloat16(v.w);
}

// ---------------------------------------------------------------------------
// Fused zx+zn via MFMA. One block per (b,c). LDS rows (stride ZNX_PAD=264):
//   rows 0..63 = nb[b,:,c,:], row 64 = x[b,c,:], rows 65..79 = 0  (bf16)
//   out(n,a) = sum_d rows(n,d) * adj(a,d);  adj computed in-register per
//   B-fragment (each adj value computed exactly once, never materialized).
// Wave w owns a-strip [w*64, w*64+64). 16x16x32 bf16 MFMA, 5 m-tiles.
#define ZNX_PAD 264  // row STRIDE in bf16: 256 data + 8 pad (132 dw == 4 mod 32)
__global__ __launch_bounds__(256) void znx_k(const float* __restrict__ x,
        const float* __restrict__ t, const float* __restrict__ denom,
        const float* __restrict__ nb, __hip_bfloat16* __restrict__ Abuf) {
    int bc = blockIdx.x;
    int b = bc >> 3, c = bc & 7;
    int tid = threadIdx.x;
    int wave = tid >> 6, lane = tid & 63;
    __shared__ float xs[F_], ts[F_];
    __shared__ __hip_bfloat16 nbB[80 * ZNX_PAD];  // 42240 B

    xs[tid] = x[(size_t)bc * F_ + tid];
    ts[tid] = t[(size_t)bc * F_ + tid];
    // stage nb rows 0..63 as bf16: thread -> row tid>>2, col segment (tid&3)*64
    {
        int r = tid >> 2, cs0 = (tid & 3) * 64;
        const float* src = nb + (((size_t)(b * N_ + r)) * C_ + c) * F_ + cs0;
        __hip_bfloat16* dst = nbB + r * ZNX_PAD + cs0;
        #pragma unroll
        for (int j = 0; j < 64; j += 4) {
            float4 v = *(const float4*)(src + j);
            dst[j + 0] = __float2bfloat16(v.x);
            dst[j + 1] = __float2bfloat16(v.y);
            dst[j + 2] = __float2bfloat16(v.z);
            dst[j + 3] = __float2bfloat16(v.w);
        }
    }
    // row 64 = x[b,c,:]
    if (tid < 64) {
        float4 v = *(const float4*)(x + (size_t)bc * F_ + tid * 4);
        __hip_bfloat16* dst = nbB + 64 * ZNX_PAD + tid * 4;
        dst[0] = __float2bfloat16(v.x);
        dst[1] = __float2bfloat16(v.y);
        dst[2] = __float2bfloat16(v.z);
        dst[3] = __float2bfloat16(v.w);
    }
    // rows 65..79 = 0 (15*264 = 3960 entries)
    {
        __hip_bfloat16 z = __float2bfloat16(0.f);
        #pragma unroll
        for (int j = 0; j < 16; ++j) {
            int o = 65 * ZNX_PAD + tid * 16 + j;
            if (o < 80 * ZNX_PAD) nbB[o] = z;
        }
    }
    __syncthreads();

    const int aq = lane & 15;       // a within 16-tile; also m-row within tile
    const int dq = lane >> 4;       // quad: k-offset dq*8; C-row dq*4+i
    #pragma unroll
    for (int atile = 0; atile < 4; ++atile) {
        int a = wave * 64 + atile * 16 + aq;
        float xa = xs[a], ta = ts[a];
        const float* drow = denom + ((size_t)b * F_ + a) * F_;
        f32x4 acc[5] = {};
        #pragma unroll
        for (int kc = 0; kc < 8; ++kc) {
            int d0 = kc * 32 + dq * 8;
            float4 xv0 = *(const float4*)(xs + d0);
            float4 xv1 = *(const float4*)(xs + d0 + 4);
            float4 tv0 = *(const float4*)(ts + d0);
            float4 tv1 = *(const float4*)(ts + d0 + 4);
            float4 dn0 = *(const float4*)(drow + d0);
            float4 dn1 = *(const float4*)(drow + d0 + 4);
            float xv[8] = {xv0.x, xv0.y, xv0.z, xv0.w, xv1.x, xv1.y, xv1.z, xv1.w};
            float tv[8] = {tv0.x, tv0.y, tv0.z, tv0.w, tv1.x, tv1.y, tv1.z, tv1.w};
            float dn[8] = {dn0.x, dn0.y, dn0.z, dn0.w, dn1.x, dn1.y, dn1.z, dn1.w};
            union { bf16x8 v; __hip_bfloat16 h[8]; } bu;
            #pragma unroll
            for (int j = 0; j < 8; ++j) {
                float g = sgnroot_dev(xa * tv[j] + xv[j] * ta);
                bu.h[j] = __float2bfloat16(g / dn[j]);
            }
            #pragma unroll
            for (int mt = 0; mt < 5; ++mt) {
                bf16x8 af = *(const bf16x8*)(nbB + (mt * 16 + aq) * ZNX_PAD
                                             + kc * 32 + dq * 8);
                acc[mt] = __builtin_amdgcn_mfma_f32_16x16x32_bf16(
                    af, bu.v, acc[mt], 0, 0, 0);
            }
        }
        // write out: C/D layout col=lane&15 (=a), row=(lane>>4)*4+i (=n part)
        int colA = c * F_ + a;
        #pragma unroll
        for (int mt = 0; mt < 4; ++mt) {
            int row = 64 + b * N_ + mt * 16 + dq * 4;
            #pragma unroll
            for (int i = 0; i < 4; ++i)
                Abuf[(size_t)(row + i) * K_ + colA] = __float2bfloat16(acc[mt][i]);
        }
        if (dq == 0)  // m-tile 4, local row 64 = the x row -> zx
            Abuf[(size_t)b * K_ + colA] = __float2bfloat16(acc[4][0]);
    }
}

// ---------------------------------------------------------------------------
// C[M_TOT, 2048] = A[M_TOT, 2048] @ B[2048, 2048]^T, bf16 inputs, fp32 out.
__global__ __launch_bounds__(256) void gemm_bf16_k(
        const __hip_bfloat16* __restrict__ A,
        const __hip_bfloat16* __restrict__ Bm,
        float* __restrict__ Cm) {
    __shared__ char ldsA[128 * 32 * 2] __attribute__((aligned(16)));  // 8KB
    __shared__ char ldsB[128 * 32 * 2] __attribute__((aligned(16)));  // 8KB
    const int t = threadIdx.x;
    const int wave = t >> 6;
    const int lane = t & 63;
    const int col0 = blockIdx.x * 128;
    const int row0 = blockIdx.y * 128;
    const int wrow0 = (wave & 1) * 64;
    const int wcol0 = (wave >> 1) * 64;

    const int rA0 = t >> 2;
    const int kc = (t & 3) * 8;
    const int grA0 = min(row0 + rA0, M_TOT - 1);
    const int grA1 = min(row0 + rA0 + 64, M_TOT - 1);
    const int gcB0 = col0 + rA0;
    const int gcB1 = col0 + rA0 + 64;
    const char* ldsA_u0 = ldsA + ((t >> 6) << 6) * 16;
    const char* ldsA_u1 = ldsA + 4096 + ((t >> 6) << 6) * 16;
    const char* ldsB_u0 = ldsB + ((t >> 6) << 6) * 16;
    const char* ldsB_u1 = ldsB + 4096 + ((t >> 6) << 6) * 16;

    f32x4 acc[4][4] = {};

    for (int k0 = 0; k0 < K_; k0 += 32) {
        __syncthreads();
        __builtin_amdgcn_global_load_lds(
            (const __attribute__((address_space(1))) void*)(A + (size_t)grA0 * K_ + k0 + kc),
            (__attribute__((address_space(3))) void*)ldsA_u0, 16, 0, 0);
        __builtin_amdgcn_global_load_lds(
            (const __attribute__((address_space(1))) void*)(A + (size_t)grA1 * K_ + k0 + kc),
            (__attribute__((address_space(3))) void*)ldsA_u1, 16, 0, 0);
        __builtin_amdgcn_global_load_lds(
            (const __attribute__((address_space(1))) void*)(Bm + (size_t)gcB0 * K_ + k0 + kc),
            (__attribute__((address_space(3))) void*)ldsB_u0, 16, 0, 0);
        __builtin_amdgcn_global_load_lds(
            (const __attribute__((address_space(1))) void*)(Bm + (size_t)gcB1 * K_ + k0 + kc),
            (__attribute__((address_space(3))) void*)ldsB_u1, 16, 0, 0);
        __syncthreads();

        bf16x8 af[4], bf[4];
        #pragma unroll
        for (int rb = 0; rb < 4; ++rb) {
            int off = (wrow0 + rb * 16 + (lane & 15)) * 64 + (lane >> 4) * 16;
            af[rb] = *(const bf16x8*)(ldsA + off);
        }
        #pragma unroll
        for (int cb = 0; cb < 4; ++cb) {
            int off = (wcol0 + cb * 16 + (lane & 15)) * 64 + (lane >> 4) * 16;
            bf[cb] = *(const bf16x8*)(ldsB + off);
        }
        #pragma unroll
        for (int rb = 0; rb < 4; ++rb)
            #pragma unroll
            for (int cb = 0; cb < 4; ++cb)
                acc[rb][cb] = __builtin_amdgcn_mfma_f32_16x16x32_bf16(
                    af[rb], bf[cb], acc[rb][cb], 0, 0, 0);
    }

    #pragma unroll
    for (int rb = 0; rb < 4; ++rb) {
        int rowbase = row0 + wrow0 + rb * 16 + (lane >> 4) * 4;
        #pragma unroll
        for (int cb = 0; cb < 4; ++cb) {
            int col = col0 + wcol0 + cb * 16 + (lane & 15);
            #pragma unroll
            for (int i = 0; i < 4; ++i) {
                int row = rowbase + i;
                if (row < M_TOT)
                    Cm[(size_t)row * NO_ + col] = acc[rb][cb][i];
            }
        }
    }
}

// ---------------------------------------------------------------------------
extern "C" void kernel_launch(void* const* d_in, const int* in_sizes, int n_in,
                              void* d_out, int out_size, void* d_ws, size_t ws_size,
                              hipStream_t stream) {
    const float* x  = (const float*)d_in[0];
    const float* nb = (const float*)d_in[1];
    const float* W1 = (const float*)d_in[2];
    const float* W2 = (const float*)d_in[3];
    const float* Wc = (const float*)d_in[4];
    float* out = (float*)d_out;
    float* ws = (float*)d_ws;

    float* s1    = ws;            // 64 f
    float* s2    = ws + 64;       // 4096 f
    float* t     = ws + 4160;     // 131072 f
    float* denom = ws + 135232;   // 4194304 f (B*F*F)
    __hip_bfloat16* Abuf = (__hip_bfloat16*)(ws + 4329536);   // 4160*2048 bf16
    __hip_bfloat16* Bbuf = Abuf + (size_t)M_TOT * K_;         // 2048*2048 bf16

    hipLaunchKernelGGL(sums_k, dim3(B_ * N_ + B_), dim3(256), 0, stream,
                       x, nb, W1, W2, s1, s2);
    hipLaunchKernelGGL(t_k, dim3(B_ * C_), dim3(256), 0, stream, nb, s1, s2, t);
    hipLaunchKernelGGL(denom_k, dim3(B_ * F_), dim3(256), 0, stream, x, t, denom);
    hipLaunchKernelGGL(wc_cvt_k, dim3((K_ * NO_) / 1024), dim3(256), 0, stream,
                       Wc, Bbuf);
    hipLaunchKernelGGL(znx_k, dim3(B_ * C_), dim3(256), 0, stream,
                       x, t, denom, nb, Abuf);
    hipLaunchKernelGGL(gemm_bf16_k, dim3(16, 33), dim3(256), 0, stream,
                       Abuf, Bbuf, out);
}

// Round 5
// 238.836 us; speedup vs baseline: 3.6241x; 1.1184x over previous
//
#include <hip/hip_runtime.h>
#include <hip/hip_bf16.h>
#include <math.h>

#define B_ 64
#define N_ 64
#define C_ 8
#define F_ 256
#define K_ 2048    // C_*F_
#define NO_ 2048   // OC_*OF_
#define M_TOT 4160 // 64 (zx rows) + 4096 (zn rows)

typedef __attribute__((ext_vector_type(8))) short bf16x8;  // 8 bf16 = 4 VGPRs
typedef __attribute__((ext_vector_type(4))) float f32x4;

// ---------------------------------------------------------------------------
// s1[b] = sum_{c,f} x[b,c,f] * w1sum[f]; s2[b,n] = sum_{c,f} nb[b,n,c,f]*w2sum[f]
__global__ __launch_bounds__(256) void sums_k(const float* __restrict__ x,
        const float* __restrict__ nb, const float* __restrict__ W1,
        const float* __restrict__ W2, float* __restrict__ s1,
        float* __restrict__ s2) {
    int blk = blockIdx.x;
    int f = threadIdx.x;
    float val;
    if (blk < B_ * N_) {
        const float* base = nb + (size_t)blk * (C_ * F_);
        float wsum = 0.f;
        #pragma unroll
        for (int k = 0; k < C_; ++k) wsum += W2[k * F_ + f];
        float cs = 0.f;
        #pragma unroll
        for (int c = 0; c < C_; ++c) cs += base[c * F_ + f];
        val = cs * wsum;
    } else {
        int b = blk - B_ * N_;
        const float* base = x + (size_t)b * (C_ * F_);
        float wsum = 0.f;
        #pragma unroll
        for (int k = 0; k < C_; ++k) wsum += W1[k * F_ + f];
        float cs = 0.f;
        #pragma unroll
        for (int c = 0; c < C_; ++c) cs += base[c * F_ + f];
        val = cs * wsum;
    }
    // wave shuffle reduce (wave64), then one cross-wave combine
    #pragma unroll
    for (int off = 32; off > 0; off >>= 1) val += __shfl_down(val, off, 64);
    __shared__ float wred[4];
    int w = f >> 6;
    if ((f & 63) == 0) wred[w] = val;
    __syncthreads();
    if (f == 0) {
        float s = wred[0] + wred[1] + wred[2] + wred[3];
        if (blk < B_ * N_) s2[blk] = s;
        else s1[blk - B_ * N_] = s;
    }
}

// ---------------------------------------------------------------------------
// t[b,c,d] = s1[b] * sum_n nb[b,n,c,d] * s2[b,n]
// 1024 threads: 4-way n-split (q = tid>>8) + LDS reduce for latency hiding.
__global__ __launch_bounds__(1024) void t_k(const float* __restrict__ nb,
        const float* __restrict__ s1, const float* __restrict__ s2,
        float* __restrict__ t) {
    int blk = blockIdx.x;  // b*C_ + c
    int b = blk / C_, c = blk % C_;
    int tid = threadIdx.x;
    int q = tid >> 8, d = tid & 255;
    const float* p = nb + ((size_t)(b * N_) * C_ + c) * F_ + d;
    const float* s2p = s2 + b * N_;
    float acc = 0.f;
    #pragma unroll
    for (int j = 0; j < 16; ++j) {
        int n = q * 16 + j;
        acc += p[(size_t)n * C_ * F_] * s2p[n];
    }
    __shared__ float part[4][F_];
    part[q][d] = acc;
    __syncthreads();
    if (tid < 256) {
        float s = part[0][d] + part[1][d] + part[2][d] + part[3][d];
        t[(size_t)blk * F_ + d] = s * s1[b];
    }
}

// ---------------------------------------------------------------------------
// rdenom[b,a,d] = 1 / (1e-7 + sum_c |sgnroot(x_a t_d + x_d t_a)|)  (reciprocal!)
__global__ __launch_bounds__(256) void denom_k(const float* __restrict__ x,
        const float* __restrict__ t, float* __restrict__ rdenom) {
    int blk = blockIdx.x;  // b*F_ + a
    int b = blk >> 8, a = blk & 255;
    int d = threadIdx.x;
    float acc = 1e-7f;
    #pragma unroll
    for (int c = 0; c < C_; ++c) {
        size_t o = ((size_t)b * C_ + c) * F_;
        float xa = x[o + a], ta = t[o + a];
        float xd = x[o + d], td = t[o + d];
        float v = xa * td + xd * ta;
        float r = __builtin_amdgcn_sqrtf(fmaxf(fabsf(v), 1e-8f));
        acc += (v != 0.f) ? r : 0.f;
    }
    rdenom[(size_t)blk * F_ + d] = __builtin_amdgcn_rcpf(acc);
}

__device__ __forceinline__ float sgnroot_dev(float v) {
    float r = __builtin_amdgcn_sqrtf(fmaxf(fabsf(v), 1e-8f));
    return (v > 0.f) ? r : ((v < 0.f) ? -r : 0.f);
}

// ---------------------------------------------------------------------------
// Wc (2048x2048 fp32) -> bf16
__global__ __launch_bounds__(256) void wc_cvt_k(const float* __restrict__ Wc,
        __hip_bfloat16* __restrict__ Bbuf) {
    int i = (blockIdx.x * 256 + threadIdx.x) * 4;
    float4 v = *(const float4*)(Wc + i);
    Bbuf[i + 0] = __float2bfloat16(v.x);
    Bbuf[i + 1] = __float2bfloat16(v.y);
    Bbuf[i + 2] = __float2bfloat16(v.z);
    Bbuf[i + 3] = __float2bfloat16(v.w);
}

// ---------------------------------------------------------------------------
// Fused zx+zn via MFMA. One block per (b,c). LDS rows (stride ZNX_PAD=264):
//   rows 0..63 = nb[b,:,c,:], row 64 = x[b,c,:], rows 65..79 = 0  (bf16)
//   out(n,a) = sum_d rows(n,d) * adj(a,d);  adj computed in-register per
//   B-fragment (each adj value computed exactly once, never materialized).
// Wave w owns a-strip [w*64, w*64+64). 16x16x32 bf16 MFMA, 5 m-tiles.
#define ZNX_PAD 264  // row STRIDE in bf16: 256 data + 8 pad (132 dw == 4 mod 32)
__global__ __launch_bounds__(256) void znx_k(const float* __restrict__ x,
        const float* __restrict__ t, const float* __restrict__ rdenom,
        const float* __restrict__ nb, __hip_bfloat16* __restrict__ Abuf) {
    int bc = blockIdx.x;
    int b = bc >> 3, c = bc & 7;
    int tid = threadIdx.x;
    int wave = tid >> 6, lane = tid & 63;
    __shared__ float xs[F_], ts[F_];
    __shared__ __hip_bfloat16 nbB[80 * ZNX_PAD];  // 42240 B

    xs[tid] = x[(size_t)bc * F_ + tid];
    ts[tid] = t[(size_t)bc * F_ + tid];
    // stage nb rows 0..63 as bf16: thread -> row tid>>2, col segment (tid&3)*64
    {
        int r = tid >> 2, cs0 = (tid & 3) * 64;
        const float* src = nb + (((size_t)(b * N_ + r)) * C_ + c) * F_ + cs0;
        __hip_bfloat16* dst = nbB + r * ZNX_PAD + cs0;
        #pragma unroll
        for (int j = 0; j < 64; j += 4) {
            float4 v = *(const float4*)(src + j);
            dst[j + 0] = __float2bfloat16(v.x);
            dst[j + 1] = __float2bfloat16(v.y);
            dst[j + 2] = __float2bfloat16(v.z);
            dst[j + 3] = __float2bfloat16(v.w);
        }
    }
    // row 64 = x[b,c,:]
    if (tid < 64) {
        float4 v = *(const float4*)(x + (size_t)bc * F_ + tid * 4);
        __hip_bfloat16* dst = nbB + 64 * ZNX_PAD + tid * 4;
        dst[0] = __float2bfloat16(v.x);
        dst[1] = __float2bfloat16(v.y);
        dst[2] = __float2bfloat16(v.z);
        dst[3] = __float2bfloat16(v.w);
    }
    // rows 65..79 = 0 (15*264 = 3960 entries)
    {
        __hip_bfloat16 z = __float2bfloat16(0.f);
        #pragma unroll
        for (int j = 0; j < 16; ++j) {
            int o = 65 * ZNX_PAD + tid * 16 + j;
            if (o < 80 * ZNX_PAD) nbB[o] = z;
        }
    }
    __syncthreads();

    const int aq = lane & 15;       // a within 16-tile; also m-row within tile
    const int dq = lane >> 4;       // quad: k-offset dq*8; C-row dq*4+i
    #pragma unroll
    for (int atile = 0; atile < 4; ++atile) {
        int a = wave * 64 + atile * 16 + aq;
        float xa = xs[a], ta = ts[a];
        const float* drow = rdenom + ((size_t)b * F_ + a) * F_;
        f32x4 acc[5] = {};
        #pragma unroll
        for (int kc = 0; kc < 8; ++kc) {
            int d0 = kc * 32 + dq * 8;
            float4 xv0 = *(const float4*)(xs + d0);
            float4 xv1 = *(const float4*)(xs + d0 + 4);
            float4 tv0 = *(const float4*)(ts + d0);
            float4 tv1 = *(const float4*)(ts + d0 + 4);
            float4 dn0 = *(const float4*)(drow + d0);
            float4 dn1 = *(const float4*)(drow + d0 + 4);
            float xv[8] = {xv0.x, xv0.y, xv0.z, xv0.w, xv1.x, xv1.y, xv1.z, xv1.w};
            float tv[8] = {tv0.x, tv0.y, tv0.z, tv0.w, tv1.x, tv1.y, tv1.z, tv1.w};
            float dn[8] = {dn0.x, dn0.y, dn0.z, dn0.w, dn1.x, dn1.y, dn1.z, dn1.w};
            union { bf16x8 v; __hip_bfloat16 h[8]; } bu;
            #pragma unroll
            for (int j = 0; j < 8; ++j) {
                float g = sgnroot_dev(xa * tv[j] + xv[j] * ta);
                bu.h[j] = __float2bfloat16(g * dn[j]);   // dn = 1/denom
            }
            #pragma unroll
            for (int mt = 0; mt < 5; ++mt) {
                bf16x8 af = *(const bf16x8*)(nbB + (mt * 16 + aq) * ZNX_PAD
                                             + kc * 32 + dq * 8);
                acc[mt] = __builtin_amdgcn_mfma_f32_16x16x32_bf16(
                    af, bu.v, acc[mt], 0, 0, 0);
            }
        }
        // write out: C/D layout col=lane&15 (=a), row=(lane>>4)*4+i (=n part)
        int colA = c * F_ + a;
        #pragma unroll
        for (int mt = 0; mt < 4; ++mt) {
            int row = 64 + b * N_ + mt * 16 + dq * 4;
            #pragma unroll
            for (int i = 0; i < 4; ++i)
                Abuf[(size_t)(row + i) * K_ + colA] = __float2bfloat16(acc[mt][i]);
        }
        if (dq == 0)  // m-tile 4, local row 64 = the x row -> zx
            Abuf[(size_t)b * K_ + colA] = __float2bfloat16(acc[4][0]);
    }
}

// ---------------------------------------------------------------------------
// C[M_TOT, 2048] = A[M_TOT, 2048] @ B[2048, 2048]^T, bf16 inputs, fp32 out.
__global__ __launch_bounds__(256) void gemm_bf16_k(
        const __hip_bfloat16* __restrict__ A,
        const __hip_bfloat16* __restrict__ Bm,
        float* __restrict__ Cm) {
    __shared__ char ldsA[128 * 32 * 2] __attribute__((aligned(16)));  // 8KB
    __shared__ char ldsB[128 * 32 * 2] __attribute__((aligned(16)));  // 8KB
    const int t = threadIdx.x;
    const int wave = t >> 6;
    const int lane = t & 63;
    const int col0 = blockIdx.x * 128;
    const int row0 = blockIdx.y * 128;
    const int wrow0 = (wave & 1) * 64;
    const int wcol0 = (wave >> 1) * 64;

    const int rA0 = t >> 2;
    const int kc = (t & 3) * 8;
    const int grA0 = min(row0 + rA0, M_TOT - 1);
    const int grA1 = min(row0 + rA0 + 64, M_TOT - 1);
    const int gcB0 = col0 + rA0;
    const int gcB1 = col0 + rA0 + 64;
    const char* ldsA_u0 = ldsA + ((t >> 6) << 6) * 16;
    const char* ldsA_u1 = ldsA + 4096 + ((t >> 6) << 6) * 16;
    const char* ldsB_u0 = ldsB + ((t >> 6) << 6) * 16;
    const char* ldsB_u1 = ldsB + 4096 + ((t >> 6) << 6) * 16;

    f32x4 acc[4][4] = {};

    for (int k0 = 0; k0 < K_; k0 += 32) {
        __syncthreads();
        __builtin_amdgcn_global_load_lds(
            (const __attribute__((address_space(1))) void*)(A + (size_t)grA0 * K_ + k0 + kc),
            (__attribute__((address_space(3))) void*)ldsA_u0, 16, 0, 0);
        __builtin_amdgcn_global_load_lds(
            (const __attribute__((address_space(1))) void*)(A + (size_t)grA1 * K_ + k0 + kc),
            (__attribute__((address_space(3))) void*)ldsA_u1, 16, 0, 0);
        __builtin_amdgcn_global_load_lds(
            (const __attribute__((address_space(1))) void*)(Bm + (size_t)gcB0 * K_ + k0 + kc),
            (__attribute__((address_space(3))) void*)ldsB_u0, 16, 0, 0);
        __builtin_amdgcn_global_load_lds(
            (const __attribute__((address_space(1))) void*)(Bm + (size_t)gcB1 * K_ + k0 + kc),
            (__attribute__((address_space(3))) void*)ldsB_u1, 16, 0, 0);
        __syncthreads();

        bf16x8 af[4], bf[4];
        #pragma unroll
        for (int rb = 0; rb < 4; ++rb) {
            int off = (wrow0 + rb * 16 + (lane & 15)) * 64 + (lane >> 4) * 16;
            af[rb] = *(const bf16x8*)(ldsA + off);
        }
        #pragma unroll
        for (int cb = 0; cb < 4; ++cb) {
            int off = (wcol0 + cb * 16 + (lane & 15)) * 64 + (lane >> 4) * 16;
            bf[cb] = *(const bf16x8*)(ldsB + off);
        }
        #pragma unroll
        for (int rb = 0; rb < 4; ++rb)
            #pragma unroll
            for (int cb = 0; cb < 4; ++cb)
                acc[rb][cb] = __builtin_amdgcn_mfma_f32_16x16x32_bf16(
                    af[rb], bf[cb], acc[rb][cb], 0, 0, 0);
    }

    #pragma unroll
    for (int rb = 0; rb < 4; ++rb) {
        int rowbase = row0 + wrow0 + rb * 16 + (lane >> 4) * 4;
        #pragma unroll
        for (int cb = 0; cb < 4; ++cb) {
            int col = col0 + wcol0 + cb * 16 + (lane & 15);
            #pragma unroll
            for (int i = 0; i < 4; ++i) {
                int row = rowbase + i;
                if (row < M_TOT)
                    Cm[(size_t)row * NO_ + col] = acc[rb][cb][i];
            }
        }
    }
}

// ---------------------------------------------------------------------------
extern "C" void kernel_launch(void* const* d_in, const int* in_sizes, int n_in,
                              void* d_out, int out_size, void* d_ws, size_t ws_size,
                              hipStream_t stream) {
    const float* x  = (const float*)d_in[0];
    const float* nb = (const float*)d_in[1];
    const float* W1 = (const float*)d_in[2];
    const float* W2 = (const float*)d_in[3];
    const float* Wc = (const float*)d_in[4];
    float* out = (float*)d_out;
    float* ws = (float*)d_ws;

    float* s1    = ws;            // 64 f
    float* s2    = ws + 64;       // 4096 f
    float* t     = ws + 4160;     // 131072 f
    float* rden  = ws + 135232;   // 4194304 f (B*F*F), stores 1/denom
    __hip_bfloat16* Abuf = (__hip_bfloat16*)(ws + 4329536);   // 4160*2048 bf16
    __hip_bfloat16* Bbuf = Abuf + (size_t)M_TOT * K_;         // 2048*2048 bf16

    hipLaunchKernelGGL(sums_k, dim3(B_ * N_ + B_), dim3(256), 0, stream,
                       x, nb, W1, W2, s1, s2);
    hipLaunchKernelGGL(t_k, dim3(B_ * C_), dim3(1024), 0, stream, nb, s1, s2, t);
    hipLaunchKernelGGL(denom_k, dim3(B_ * F_), dim3(256), 0, stream, x, t, rden);
    hipLaunchKernelGGL(wc_cvt_k, dim3((K_ * NO_) / 1024), dim3(256), 0, stream,
                       Wc, Bbuf);
    hipLaunchKernelGGL(znx_k, dim3(B_ * C_), dim3(256), 0, stream,
                       x, t, rden, nb, Abuf);
    hipLaunchKernelGGL(gemm_bf16_k, dim3(16, 33), dim3(256), 0, stream,
                       Abuf, Bbuf, out);
}